// Round 8
// baseline (71.461 us; speedup 1.0000x reference)
//
#include <hip/hip_runtime.h>
#include <hip/hip_bf16.h>

#define EMBED   1024
#define NHEADS  16
#define HDIM    64
#define BATCH   2
#define SEQ     2048
#define LOG2E   1.44269504088896340736f

typedef __attribute__((ext_vector_type(8))) short bf16x8;
typedef __attribute__((ext_vector_type(4))) short bf16x4;
typedef __attribute__((ext_vector_type(4))) float f32x4;
typedef __attribute__((ext_vector_type(16))) float f32x16;
using bf16 = __hip_bfloat16;

__device__ __forceinline__ float fast_exp2(float x) {
    float r; asm("v_exp_f32 %0, %1" : "=v"(r) : "v"(x)); return r;
}

// async global->LDS, 16B per lane; LDS dest is wave-uniform base + lane*16
__device__ __forceinline__ void gload_lds16(const bf16* g, bf16* l) {
    __builtin_amdgcn_global_load_lds(
        (const __attribute__((address_space(1))) void*)g,
        (__attribute__((address_space(3))) void*)l, 16, 0, 0);
}

// ---------------------------------------------------------------------------
// Fused fp32->bf16 prep: x (scale 1), wq (scale beta*log2e), wk (scale 1).
// Thread (0,0) also zeroes the energy accumulator (replaces a memset launch).
// ---------------------------------------------------------------------------
__global__ __launch_bounds__(256) void prep_kernel(const float* __restrict__ x,
                                                   const float* __restrict__ wq,
                                                   const float* __restrict__ wk,
                                                   const float* __restrict__ betas,
                                                   bf16* __restrict__ xb,
                                                   bf16* __restrict__ wqb,
                                                   bf16* __restrict__ wkb,
                                                   float* __restrict__ out) {
    const size_t NX = (size_t)BATCH * SEQ * EMBED;
    const size_t NW = (size_t)EMBED * EMBED;
    if (blockIdx.x == 0 && threadIdx.x == 0) out[0] = 0.f;
    size_t i4 = ((size_t)blockIdx.x * 256 + threadIdx.x) * 4;
    const float* src;
    bf16* dst;
    float sc;
    if (i4 < NX)            { src = x  + i4; dst = xb  + i4; sc = 1.0f; }
    else if (i4 < NX + NW)  { size_t i = i4 - NX; src = wq + i; dst = wqb + i;
                              sc = betas[i >> 16] * LOG2E; }   // 64*1024 elems/head
    else                    { size_t i = i4 - NX - NW; src = wk + i; dst = wkb + i; sc = 1.0f; }
    float4 v = *reinterpret_cast<const float4*>(src);
    bf16 o[4];
    o[0] = __float2bfloat16(v.x * sc);
    o[1] = __float2bfloat16(v.y * sc);
    o[2] = __float2bfloat16(v.z * sc);
    o[3] = __float2bfloat16(v.w * sc);
    *reinterpret_cast<bf16x4*>(dst) = *reinterpret_cast<const bf16x4*>(o);
}

// ---------------------------------------------------------------------------
// Fused q+k projection GEMM via MFMA. 128x128 tile, 256 threads (2x2 waves,
// 64x64/wave), global_load_lds 16B staging, LDS DOUBLE-BUFFERED with ONE
// barrier per K-step (2-phase): issue next tile's loads, compute current,
// then __syncthreads() (implicit vmcnt(0) drain lands after compute has
// covered the load latency). blockIdx.y < 8 -> wq/qout, else wk/kout.
// ---------------------------------------------------------------------------
__global__ __launch_bounds__(256) void proj_mfma(const bf16* __restrict__ xb,
                                                 const bf16* __restrict__ wqb,
                                                 const bf16* __restrict__ wkb,
                                                 bf16* __restrict__ qout,
                                                 bf16* __restrict__ kout) {
    __shared__ __align__(16) bf16 As[2][128][64];
    __shared__ __align__(16) bf16 Bs[2][128][64];
    const int tid  = threadIdx.x;
    const int lane = tid & 63;
    const int wave = tid >> 6;
    const int wr = wave >> 1, wc = wave & 1;
    const int m0 = blockIdx.x * 128;
    const bool isq = (blockIdx.y < 8);
    const int n0 = (blockIdx.y & 7) * 128;
    const bf16* wb = isq ? wqb : wkb;
    bf16* outb = isq ? qout : kout;
    const int srow = lane >> 3;          // row within 8-row chunk
    const int scol = (lane & 7) * 8;     // element col of this lane's 16B

    f32x4 acc[4][4] = {};

    // prologue: stage k-tile 0 into buffer 0
    #pragma unroll
    for (int i = 0; i < 4; ++i) {
        int j = wave * 4 + i;            // chunk 0..15 (8 rows each)
        gload_lds16(&xb[(size_t)(m0 + j * 8 + srow) * EMBED + scol], &As[0][j * 8][0]);
        gload_lds16(&wb[(size_t)(n0 + j * 8 + srow) * EMBED + scol], &Bs[0][j * 8][0]);
    }
    __syncthreads();                     // drains vmcnt: tile 0 resident

    for (int kt = 0; kt < EMBED / 64; ++kt) {
        const int cur = kt & 1;
        if (kt + 1 < EMBED / 64) {       // issue next tile first (overlaps MFMA)
            const int k0 = (kt + 1) * 64;
            #pragma unroll
            for (int i = 0; i < 4; ++i) {
                int j = wave * 4 + i;
                gload_lds16(&xb[(size_t)(m0 + j * 8 + srow) * EMBED + k0 + scol], &As[cur ^ 1][j * 8][0]);
                gload_lds16(&wb[(size_t)(n0 + j * 8 + srow) * EMBED + k0 + scol], &Bs[cur ^ 1][j * 8][0]);
            }
        }
        #pragma unroll
        for (int ks = 0; ks < 2; ++ks) {
            bf16x8 af[4], bfr[4];
            #pragma unroll
            for (int a = 0; a < 4; ++a)
                af[a] = *reinterpret_cast<const bf16x8*>(&As[cur][wr * 64 + a * 16 + (lane & 15)][ks * 32 + (lane >> 4) * 8]);
            #pragma unroll
            for (int b2 = 0; b2 < 4; ++b2)
                bfr[b2] = *reinterpret_cast<const bf16x8*>(&Bs[cur][wc * 64 + b2 * 16 + (lane & 15)][ks * 32 + (lane >> 4) * 8]);
            #pragma unroll
            for (int a = 0; a < 4; ++a)
                #pragma unroll
                for (int b2 = 0; b2 < 4; ++b2)
                    acc[a][b2] = __builtin_amdgcn_mfma_f32_16x16x32_bf16(af[a], bfr[b2], acc[a][b2], 0, 0, 0);
        }
        __syncthreads();                 // reads of cur done + next tile drained
    }
    #pragma unroll
    for (int a = 0; a < 4; ++a)
        #pragma unroll
        for (int b2 = 0; b2 < 4; ++b2)
            #pragma unroll
            for (int j = 0; j < 4; ++j) {
                int row = m0 + wr * 64 + a * 16 + (lane >> 4) * 4 + j;
                int col = n0 + wc * 64 + b2 * 16 + (lane & 15);
                outb[(size_t)row * EMBED + col] = __float2bfloat16(acc[a][b2][j]);
            }
}

// ---------------------------------------------------------------------------
// Fused masked exp-sum + lse + energy. One block = (b, h, 128 q rows), FULL
// k-range (no k-split, no finalize kernel). 4 waves own 32 q rows each.
// 32x32x16 MFMA, mfma(A=K, B=Q): D col = lane&31 -> q row (lane-local sums),
// row = (r&3)+8*(r>>2)+4*(lane>>5) -> k row. K double-buffered in padded LDS
// [2][128][72], reg-staged, ONE barrier per tile: write tile it+1 from regs,
// prefetch tile it+2, compute tile it, barrier. Diagonal masked in the single
// wave-uniform diagonal subtile. Fixed m=0 (scores O(0.05): no overflow).
// Epilogue: lse = log(psum), energy atomicAdd -- finalize kernel eliminated.
// ---------------------------------------------------------------------------
__global__ __launch_bounds__(256, 4) void attn_energy(const bf16* __restrict__ q,
                                                      const bf16* __restrict__ k,
                                                      const float* __restrict__ betas,
                                                      float* __restrict__ out) {
    __shared__ __align__(16) bf16 Ks[2][128][72];
    const int tid  = threadIdx.x;
    const int lane = tid & 63;
    const int wave = tid >> 6;
    const int blk = blockIdx.x;          // (b*16+h)*16 + qt
    const int qt = blk & 15;
    const int h  = (blk >> 4) & 15;
    const int b  = blk >> 8;
    const int n0 = qt * 128 + wave * 32; // this wave's 32 q rows
    const bf16* qbase = q + (size_t)(b * SEQ) * EMBED + h * HDIM;
    const bf16* kbase = k + (size_t)(b * SEQ) * EMBED + h * HDIM;
    const int rl = lane & 31;

    // Q fragments: row n0 + rl, k = ks2*16 + (lane>>5)*8  (verified R5 map)
    bf16x8 qf[4];
    #pragma unroll
    for (int ks2 = 0; ks2 < 4; ++ks2)
        qf[ks2] = *reinterpret_cast<const bf16x8*>(
            &qbase[(size_t)(n0 + rl) * EMBED + ks2 * 16 + (lane >> 5) * 8]);

    f32x4 psv = {};

    // K staging: 128 rows x 64 cols per tile; 4x bf16x8 per thread
    const int sr = tid >> 3;             // 0..31
    const int sc = (tid & 7) * 8;
    bf16x8 stg[4];
    #pragma unroll
    for (int c = 0; c < 4; ++c)          // tile 0
        stg[c] = *reinterpret_cast<const bf16x8*>(&kbase[(size_t)(c * 32 + sr) * EMBED + sc]);
    #pragma unroll
    for (int c = 0; c < 4; ++c)
        *reinterpret_cast<bf16x8*>(&Ks[0][c * 32 + sr][sc]) = stg[c];
    #pragma unroll
    for (int c = 0; c < 4; ++c)          // tile 1 into regs
        stg[c] = *reinterpret_cast<const bf16x8*>(&kbase[(size_t)(128 + c * 32 + sr) * EMBED + sc]);
    __syncthreads();

    for (int it = 0; it < SEQ / 128; ++it) {
        const int cur = it & 1;
        const int m0 = it * 128;
        if (it + 1 < SEQ / 128) {        // write tile it+1; prefetch tile it+2
            #pragma unroll
            for (int c = 0; c < 4; ++c)
                *reinterpret_cast<bf16x8*>(&Ks[cur ^ 1][c * 32 + sr][sc]) = stg[c];
            if (it + 2 < SEQ / 128) {
                #pragma unroll
                for (int c = 0; c < 4; ++c)
                    stg[c] = *reinterpret_cast<const bf16x8*>(
                        &kbase[(size_t)((it + 2) * 128 + c * 32 + sr) * EMBED + sc]);
            }
        }

        #pragma unroll
        for (int t = 0; t < 4; ++t) {    // k subtiles of 32 rows
            bf16x8 kf[4];
            #pragma unroll
            for (int ks2 = 0; ks2 < 4; ++ks2)
                kf[ks2] = *reinterpret_cast<const bf16x8*>(
                    &Ks[cur][t * 32 + rl][ks2 * 16 + (lane >> 5) * 8]);
            f32x16 acc = {};
            __builtin_amdgcn_s_setprio(1);
            #pragma unroll
            for (int ks2 = 0; ks2 < 4; ++ks2)
                acc = __builtin_amdgcn_mfma_f32_32x32x16_bf16(kf[ks2], qf[ks2], acc, 0, 0, 0);
            __builtin_amdgcn_s_setprio(0);
            if ((m0 + t * 32) == n0) {   // diagonal subtile (once per wave)
                #pragma unroll
                for (int r = 0; r < 16; ++r) {
                    int crow = (r & 3) + 8 * (r >> 2) + 4 * (lane >> 5);
                    float e = fast_exp2(acc[r]);
                    psv[r & 3] += (crow == rl) ? 0.f : e;
                }
            } else {
                #pragma unroll
                for (int r = 0; r < 16; ++r)
                    psv[r & 3] += fast_exp2(acc[r]);
            }
        }
        __syncthreads();                 // cur reads done + it+1 writes visible
    }

    // psum per q row (lane & lane+32 duplicate), then lse and energy
    float psum = (psv[0] + psv[1]) + (psv[2] + psv[3]);
    psum += __shfl_xor(psum, 32);
    const float beta = betas[h];
    float v = (lane < 32) ? (logf(psum) / beta) : 0.f;
    #pragma unroll
    for (int off = 1; off < 64; off <<= 1) v += __shfl_xor(v, off);
    __shared__ float ws[4];
    if (lane == 0) ws[wave] = v;
    __syncthreads();
    if (tid == 0)
        atomicAdd(out, -(ws[0] + ws[1] + ws[2] + ws[3]) / (float)(BATCH * SEQ));
}

extern "C" void kernel_launch(void* const* d_in, const int* in_sizes, int n_in,
                              void* d_out, int out_size, void* d_ws, size_t ws_size,
                              hipStream_t stream) {
    const float* x     = (const float*)d_in[0];
    const float* wk    = (const float*)d_in[1];
    const float* wq    = (const float*)d_in[2];
    const float* betas = (const float*)d_in[3];
    float* out = (float*)d_out;

    const size_t NX = (size_t)BATCH * SEQ * EMBED;   // 4,194,304
    const size_t NW = (size_t)EMBED * EMBED;         // 1,048,576

    bf16* xb   = (bf16*)d_ws;                        // 8 MB
    bf16* wqb  = xb + NX;                            // 2 MB
    bf16* wkb  = wqb + NW;                           // 2 MB
    bf16* qb   = wkb + NW;                           // 8 MB
    bf16* kb   = qb + NX;                            // 8 MB

    prep_kernel<<<(int)((NX + 2 * NW) / 4 / 256), 256, 0, stream>>>(x, wq, wk, betas, xb, wqb, wkb, out);

    dim3 gproj(BATCH * SEQ / 128, 2 * EMBED / 128);  // (32, 16)
    proj_mfma<<<gproj, 256, 0, stream>>>(xb, wqb, wkb, qb, kb);

    attn_energy<<<BATCH * NHEADS * (SEQ / 128), 256, 0, stream>>>(qb, kb, betas, out);
}

// Round 9
// 63.881 us; speedup vs baseline: 1.1187x; 1.1187x over previous
//
#include <hip/hip_runtime.h>
#include <hip/hip_bf16.h>

#define EMBED   1024
#define NHEADS  16
#define HDIM    64
#define BATCH   2
#define SEQ     2048
#define LOG2E   1.44269504088896340736f

typedef __attribute__((ext_vector_type(8))) short bf16x8;
typedef __attribute__((ext_vector_type(4))) short bf16x4;
typedef __attribute__((ext_vector_type(4))) float f32x4;
typedef __attribute__((ext_vector_type(16))) float f32x16;
using bf16 = __hip_bfloat16;

__device__ __forceinline__ float fast_exp2(float x) {
    float r; asm("v_exp_f32 %0, %1" : "=v"(r) : "v"(x)); return r;
}

// async global->LDS, 16B per lane; LDS dest is wave-uniform base + lane*16
__device__ __forceinline__ void gload_lds16(const bf16* g, bf16* l) {
    __builtin_amdgcn_global_load_lds(
        (const __attribute__((address_space(1))) void*)g,
        (__attribute__((address_space(3))) void*)l, 16, 0, 0);
}

// ---------------------------------------------------------------------------
// Fused fp32->bf16 prep: x (scale 1), wq (scale beta*log2e), wk (scale 1).
// Thread (0,0) also zeroes the energy accumulator (replaces a memset launch).
// ---------------------------------------------------------------------------
__global__ __launch_bounds__(256) void prep_kernel(const float* __restrict__ x,
                                                   const float* __restrict__ wq,
                                                   const float* __restrict__ wk,
                                                   const float* __restrict__ betas,
                                                   bf16* __restrict__ xb,
                                                   bf16* __restrict__ wqb,
                                                   bf16* __restrict__ wkb,
                                                   float* __restrict__ out) {
    const size_t NX = (size_t)BATCH * SEQ * EMBED;
    const size_t NW = (size_t)EMBED * EMBED;
    if (blockIdx.x == 0 && threadIdx.x == 0) out[0] = 0.f;
    size_t i4 = ((size_t)blockIdx.x * 256 + threadIdx.x) * 4;
    const float* src;
    bf16* dst;
    float sc;
    if (i4 < NX)            { src = x  + i4; dst = xb  + i4; sc = 1.0f; }
    else if (i4 < NX + NW)  { size_t i = i4 - NX; src = wq + i; dst = wqb + i;
                              sc = betas[i >> 16] * LOG2E; }   // 64*1024 elems/head
    else                    { size_t i = i4 - NX - NW; src = wk + i; dst = wkb + i; sc = 1.0f; }
    float4 v = *reinterpret_cast<const float4*>(src);
    bf16 o[4];
    o[0] = __float2bfloat16(v.x * sc);
    o[1] = __float2bfloat16(v.y * sc);
    o[2] = __float2bfloat16(v.z * sc);
    o[3] = __float2bfloat16(v.w * sc);
    *reinterpret_cast<bf16x4*>(dst) = *reinterpret_cast<const bf16x4*>(o);
}

// ---------------------------------------------------------------------------
// Fused q+k projection GEMM via MFMA. 128x128 tile, 256 threads (2x2 waves),
// global_load_lds 16B staging, LDS double-buffered, and the T4 counted-vmcnt
// pipeline: per K-step {s_waitcnt vmcnt(8); raw s_barrier; ds_read+MFMA;
// raw s_barrier; stage tile kt+2}. Next tile's 8 loads stay in flight ACROSS
// the barrier (never drained to 0 until the last iter) -- removes the
// __syncthreads implicit vmcnt(0) drain that made R8's dbuf neutral.
// blockIdx.y < 8 -> wq/qout, else wk/kout.
// ---------------------------------------------------------------------------
__global__ __launch_bounds__(256) void proj_mfma(const bf16* __restrict__ xb,
                                                 const bf16* __restrict__ wqb,
                                                 const bf16* __restrict__ wkb,
                                                 bf16* __restrict__ qout,
                                                 bf16* __restrict__ kout) {
    __shared__ __align__(16) bf16 As[2][128][64];
    __shared__ __align__(16) bf16 Bs[2][128][64];
    const int tid  = threadIdx.x;
    const int lane = tid & 63;
    const int wave = tid >> 6;
    const int wr = wave >> 1, wc = wave & 1;
    const int m0 = blockIdx.x * 128;
    const bool isq = (blockIdx.y < 8);
    const int n0 = (blockIdx.y & 7) * 128;
    const bf16* wb = isq ? wqb : wkb;
    bf16* outb = isq ? qout : kout;
    const int srow = lane >> 3;          // row within 8-row chunk
    const int scol = (lane & 7) * 8;     // element col of this lane's 16B

    f32x4 acc[4][4] = {};

    auto stage = [&](int kt, int buf) {  // 8 gload_lds per thread (4 A + 4 B)
        const int k0 = kt * 64;
        #pragma unroll
        for (int i = 0; i < 4; ++i) {
            int j = wave * 4 + i;        // chunk 0..15 (8 rows each)
            gload_lds16(&xb[(size_t)(m0 + j * 8 + srow) * EMBED + k0 + scol], &As[buf][j * 8][0]);
            gload_lds16(&wb[(size_t)(n0 + j * 8 + srow) * EMBED + k0 + scol], &Bs[buf][j * 8][0]);
        }
    };

    stage(0, 0);                         // 8 outstanding
    stage(1, 1);                         // 16 outstanding

    for (int kt = 0; kt < EMBED / 64; ++kt) {
        const int cur = kt & 1;
        // own oldest 8 (= tile kt) landed; tile kt+1's 8 stay in flight
        if (kt < EMBED / 64 - 1) asm volatile("s_waitcnt vmcnt(8)" ::: "memory");
        else                     asm volatile("s_waitcnt vmcnt(0)" ::: "memory");
        __builtin_amdgcn_s_barrier();    // block-wide: buffer cur fully staged

        #pragma unroll
        for (int ks = 0; ks < 2; ++ks) {
            bf16x8 af[4], bfr[4];
            #pragma unroll
            for (int a = 0; a < 4; ++a)
                af[a] = *reinterpret_cast<const bf16x8*>(&As[cur][wr * 64 + a * 16 + (lane & 15)][ks * 32 + (lane >> 4) * 8]);
            #pragma unroll
            for (int b2 = 0; b2 < 4; ++b2)
                bfr[b2] = *reinterpret_cast<const bf16x8*>(&Bs[cur][wc * 64 + b2 * 16 + (lane & 15)][ks * 32 + (lane >> 4) * 8]);
            #pragma unroll
            for (int a = 0; a < 4; ++a)
                #pragma unroll
                for (int b2 = 0; b2 < 4; ++b2)
                    acc[a][b2] = __builtin_amdgcn_mfma_f32_16x16x32_bf16(af[a], bfr[b2], acc[a][b2], 0, 0, 0);
        }
        __builtin_amdgcn_s_barrier();    // all waves' reads of cur done
        if (kt + 2 < EMBED / 64) stage(kt + 2, cur);   // overwrite cur safely
    }

    #pragma unroll
    for (int a = 0; a < 4; ++a)
        #pragma unroll
        for (int b2 = 0; b2 < 4; ++b2)
            #pragma unroll
            for (int j = 0; j < 4; ++j) {
                int row = m0 + wr * 64 + a * 16 + (lane >> 4) * 4 + j;
                int col = n0 + wc * 64 + b2 * 16 + (lane & 15);
                outb[(size_t)row * EMBED + col] = __float2bfloat16(acc[a][b2][j]);
            }
}

// ---------------------------------------------------------------------------
// Fused masked exp-sum + lse + energy (unchanged from R8). One block =
// (b, h, 128 q rows), full k-range. 4 waves own 32 q rows each. 32x32x16
// MFMA, mfma(A=K, B=Q): D col = lane&31 -> q row, row = (r&3)+8*(r>>2)+
// 4*(lane>>5) -> k row. K double-buffered in padded LDS, reg-staged.
// ---------------------------------------------------------------------------
__global__ __launch_bounds__(256, 4) void attn_energy(const bf16* __restrict__ q,
                                                      const bf16* __restrict__ k,
                                                      const float* __restrict__ betas,
                                                      float* __restrict__ out) {
    __shared__ __align__(16) bf16 Ks[2][128][72];
    const int tid  = threadIdx.x;
    const int lane = tid & 63;
    const int wave = tid >> 6;
    const int blk = blockIdx.x;          // (b*16+h)*16 + qt
    const int qt = blk & 15;
    const int h  = (blk >> 4) & 15;
    const int b  = blk >> 8;
    const int n0 = qt * 128 + wave * 32; // this wave's 32 q rows
    const bf16* qbase = q + (size_t)(b * SEQ) * EMBED + h * HDIM;
    const bf16* kbase = k + (size_t)(b * SEQ) * EMBED + h * HDIM;
    const int rl = lane & 31;

    bf16x8 qf[4];
    #pragma unroll
    for (int ks2 = 0; ks2 < 4; ++ks2)
        qf[ks2] = *reinterpret_cast<const bf16x8*>(
            &qbase[(size_t)(n0 + rl) * EMBED + ks2 * 16 + (lane >> 5) * 8]);

    f32x4 psv = {};

    const int sr = tid >> 3;             // 0..31
    const int sc = (tid & 7) * 8;
    bf16x8 stg[4];
    #pragma unroll
    for (int c = 0; c < 4; ++c)          // tile 0
        stg[c] = *reinterpret_cast<const bf16x8*>(&kbase[(size_t)(c * 32 + sr) * EMBED + sc]);
    #pragma unroll
    for (int c = 0; c < 4; ++c)
        *reinterpret_cast<bf16x8*>(&Ks[0][c * 32 + sr][sc]) = stg[c];
    #pragma unroll
    for (int c = 0; c < 4; ++c)          // tile 1 into regs
        stg[c] = *reinterpret_cast<const bf16x8*>(&kbase[(size_t)(128 + c * 32 + sr) * EMBED + sc]);
    __syncthreads();

    for (int it = 0; it < SEQ / 128; ++it) {
        const int cur = it & 1;
        const int m0 = it * 128;
        if (it + 1 < SEQ / 128) {        // write tile it+1; prefetch tile it+2
            #pragma unroll
            for (int c = 0; c < 4; ++c)
                *reinterpret_cast<bf16x8*>(&Ks[cur ^ 1][c * 32 + sr][sc]) = stg[c];
            if (it + 2 < SEQ / 128) {
                #pragma unroll
                for (int c = 0; c < 4; ++c)
                    stg[c] = *reinterpret_cast<const bf16x8*>(
                        &kbase[(size_t)((it + 2) * 128 + c * 32 + sr) * EMBED + sc]);
            }
        }

        #pragma unroll
        for (int t = 0; t < 4; ++t) {    // k subtiles of 32 rows
            bf16x8 kf[4];
            #pragma unroll
            for (int ks2 = 0; ks2 < 4; ++ks2)
                kf[ks2] = *reinterpret_cast<const bf16x8*>(
                    &Ks[cur][t * 32 + rl][ks2 * 16 + (lane >> 5) * 8]);
            f32x16 acc = {};
            __builtin_amdgcn_s_setprio(1);
            #pragma unroll
            for (int ks2 = 0; ks2 < 4; ++ks2)
                acc = __builtin_amdgcn_mfma_f32_32x32x16_bf16(kf[ks2], qf[ks2], acc, 0, 0, 0);
            __builtin_amdgcn_s_setprio(0);
            if ((m0 + t * 32) == n0) {   // diagonal subtile (once per wave)
                #pragma unroll
                for (int r = 0; r < 16; ++r) {
                    int crow = (r & 3) + 8 * (r >> 2) + 4 * (lane >> 5);
                    float e = fast_exp2(acc[r]);
                    psv[r & 3] += (crow == rl) ? 0.f : e;
                }
            } else {
                #pragma unroll
                for (int r = 0; r < 16; ++r)
                    psv[r & 3] += fast_exp2(acc[r]);
            }
        }
        __syncthreads();                 // cur reads done + it+1 writes visible
    }

    float psum = (psv[0] + psv[1]) + (psv[2] + psv[3]);
    psum += __shfl_xor(psum, 32);
    const float beta = betas[h];
    float v = (lane < 32) ? (logf(psum) / beta) : 0.f;
    #pragma unroll
    for (int off = 1; off < 64; off <<= 1) v += __shfl_xor(v, off);
    __shared__ float ws[4];
    if (lane == 0) ws[wave] = v;
    __syncthreads();
    if (tid == 0)
        atomicAdd(out, -(ws[0] + ws[1] + ws[2] + ws[3]) / (float)(BATCH * SEQ));
}

extern "C" void kernel_launch(void* const* d_in, const int* in_sizes, int n_in,
                              void* d_out, int out_size, void* d_ws, size_t ws_size,
                              hipStream_t stream) {
    const float* x     = (const float*)d_in[0];
    const float* wk    = (const float*)d_in[1];
    const float* wq    = (const float*)d_in[2];
    const float* betas = (const float*)d_in[3];
    float* out = (float*)d_out;

    const size_t NX = (size_t)BATCH * SEQ * EMBED;   // 4,194,304
    const size_t NW = (size_t)EMBED * EMBED;         // 1,048,576

    bf16* xb   = (bf16*)d_ws;                        // 8 MB
    bf16* wqb  = xb + NX;                            // 2 MB
    bf16* wkb  = wqb + NW;                           // 2 MB
    bf16* qb   = wkb + NW;                           // 8 MB
    bf16* kb   = qb + NX;                            // 8 MB

    prep_kernel<<<(int)((NX + 2 * NW) / 4 / 256), 256, 0, stream>>>(x, wq, wk, betas, xb, wqb, wkb, out);

    dim3 gproj(BATCH * SEQ / 128, 2 * EMBED / 128);  // (32, 16)
    proj_mfma<<<gproj, 256, 0, stream>>>(xb, wqb, wkb, qb, kb);

    attn_energy<<<BATCH * NHEADS * (SEQ / 128), 256, 0, stream>>>(qb, kb, betas, out);
}